// Round 6
// baseline (344.280 us; speedup 1.0000x reference)
//
#include <hip/hip_runtime.h>

// Problem constants (fixed by setup_inputs in the reference; fp32 world)
#define B_    16
#define N_    1536
#define C_    768
#define N0_   3072
#define H_    64
#define W_    48
#define HW_   (H_ * W_)        // 3072
#define NPTS  (B_ * N0_)       // 49152
#define NTOK  (B_ * N_)        // 24576
#define NPIX  (B_ * HW_)       // 49152
#define NSCAN (NPIX + NTOK)    // 73728 = 288 * 256
#define NBP   (NPIX / 256)     // 192
#define NBALL (NSCAN / 256)    // 288
#define EPS_  1e-6f
#define TY_   4                // conv tile rows per block
#define TX_   8                // conv tile cols per block
#define NTILE ((W_ / TX_) * (H_ / TY_))   // 96 tiles per batch
#define NBCV  (B_ * NTILE)                // 1536 conv blocks (divisible by 8)
#define NBPT  (NPTS / 256)                // 192 point blocks

// Bijective XCD swizzle (grid % 8 == 0): XCD g gets the contiguous logical
// range [g*(n/8), (g+1)*(n/8)) -> batch b lands on XCD b/2 in ALL kernels,
// so producer writes and consumer reads of a batch share the same L2.
__device__ __forceinline__ int xcd_swz(int bid, int n) {
    return (bid & 7) * (n >> 3) + (bid >> 3);
}

// ---------------- per-point precompute + histograms + wsum  (+ wT transpose) --
__global__ void k_pre(const float* __restrict__ loc_orig,
                      const int* __restrict__ idx_agg,
                      const float* __restrict__ agg_w,
                      const float* __restrict__ conv_w, float* __restrict__ wT,
                      int* __restrict__ pixkey, int4* __restrict__ ofs4,
                      float* __restrict__ wxa, float* __restrict__ wya,
                      float* __restrict__ wa,
                      int* __restrict__ cnt_pix, int* __restrict__ cnt_tok,
                      float* __restrict__ wsum) {
    int bid = blockIdx.x;
    if (bid >= NBPT) {                 // tail blocks: transpose conv weights
        int i = (bid - NBPT) * 256 + threadIdx.x;
        if (i < C_ * 9) { int c = i / 9, k = i - c * 9; wT[k * C_ + c] = conv_w[i]; }
        return;
    }
    int i = bid * 256 + threadIdx.x;   // < NPTS
    int b = i / N0_;
    float lx = loc_orig[2 * (size_t)i];
    float ly = loc_orig[2 * (size_t)i + 1];
    lx = fminf(fmaxf(lx, -1.f), 1.f);
    ly = fminf(fmaxf(ly, -1.f), 1.f);
    float px = 0.5f * (lx + 1.f) * (float)W_ - 0.5f;   // matches np ref exactly
    float py = 0.5f * (ly + 1.f) * (float)H_ - 0.5f;
    // nearest pixel (round-half-even == np.round)
    int ixn = min(max((int)rintf(px), 0), W_ - 1);
    int iyn = min(max((int)rintf(py), 0), H_ - 1);
    int pk = b * HW_ + iyn * W_ + ixn;
    pixkey[i] = pk;
    // bilinear corners (clipped), weights per reference (may be negative at edges)
    int x0 = min(max((int)floorf(px), 0), W_ - 1);
    int x1 = min(x0 + 1, W_ - 1);
    int y0 = min(max((int)floorf(py), 0), H_ - 1);
    int y1 = min(y0 + 1, H_ - 1);
    wxa[i] = fminf((float)x1, px) - (float)x0;
    wya[i] = fminf((float)y1, py) - (float)y0;
    ofs4[i] = make_int4(y0 * W_ + x0, y0 * W_ + x1, y1 * W_ + x0, y1 * W_ + x1);
    float w = agg_w[i];
    wa[i] = w;
    atomicAdd(&cnt_pix[pk], 1);
    int tk = b * N_ + idx_agg[i];
    atomicAdd(&cnt_tok[tk], 1);
    atomicAdd(&wsum[tk], w);
}

// ---------------- hierarchical scan over contiguous cnt_pix|cnt_tok -----------
__global__ __launch_bounds__(256)
void k_scanA(const int* __restrict__ cnt, int* __restrict__ pre, int* __restrict__ bsum) {
    __shared__ int sh[256];
    int b = blockIdx.x, t = threadIdx.x;
    int i = b * 256 + t;
    int v = cnt[i];
    sh[t] = v;
    __syncthreads();
    for (int d = 1; d < 256; d <<= 1) {
        int x = sh[t];
        int y = (t >= d) ? sh[t - d] : 0;
        __syncthreads();
        sh[t] = x + y;
        __syncthreads();
    }
    pre[i] = sh[t] - v;            // exclusive within block
    if (t == 255) bsum[b] = sh[255];
}

__global__ __launch_bounds__(256)
void k_scanB(const int* __restrict__ bsum, int* __restrict__ bbase,
             int* __restrict__ off_pix, int* __restrict__ off_tok) {
    __shared__ int sh[256];
    int t = threadIdx.x;
    int v = (t < NBP) ? bsum[t] : 0;
    sh[t] = v;
    __syncthreads();
    for (int d = 1; d < 256; d <<= 1) {
        int x = sh[t];
        int y = (t >= d) ? sh[t - d] : 0;
        __syncthreads();
        sh[t] = x + y;
        __syncthreads();
    }
    if (t < NBP) bbase[t] = sh[t] - v;
    __syncthreads();
    int nbt = NBALL - NBP;
    v = (t < nbt) ? bsum[NBP + t] : 0;
    sh[t] = v;
    __syncthreads();
    for (int d = 1; d < 256; d <<= 1) {
        int x = sh[t];
        int y = (t >= d) ? sh[t - d] : 0;
        __syncthreads();
        sh[t] = x + y;
        __syncthreads();
    }
    if (t < nbt) bbase[NBP + t] = sh[t] - v;
    if (t == 0) { off_pix[NPIX] = NPTS; off_tok[NTOK] = NPTS; }
}

__global__ __launch_bounds__(256)
void k_scanC(const int* __restrict__ pre, const int* __restrict__ bbase,
             int* __restrict__ off_pix, int* __restrict__ cur_pix,
             int* __restrict__ off_tok, int* __restrict__ cur_tok) {
    int b = blockIdx.x, t = threadIdx.x;
    int i = b * 256 + t;
    int val = pre[i] + bbase[b];
    if (b < NBP) { off_pix[i] = val; cur_pix[i] = val; }
    else { int j = i - NPIX; off_tok[j] = val; cur_tok[j] = val; }
}

// ---------------- CSR fill (R3 semantics: list_tok indirection) ---------------
__global__ void k_fill(const int* __restrict__ pixkey, const int* __restrict__ idx_agg,
                       const float* __restrict__ wxa, const float* __restrict__ wya,
                       const float* __restrict__ wa, const float* __restrict__ wsum,
                       int* __restrict__ cur_pix, int* __restrict__ cur_tok,
                       int* __restrict__ list_pix, int* __restrict__ list_tok,
                       float4* __restrict__ wts4) {
    int i = blockIdx.x * blockDim.x + threadIdx.x;
    if (i >= NPTS) return;
    int b = i / N0_;
    int tok = idx_agg[i];
    int tk = b * N_ + tok;
    int s1 = atomicAdd(&cur_pix[pixkey[i]], 1);
    list_pix[s1] = tk;                 // direct x-row index for scatter
    int s2 = atomicAdd(&cur_tok[tk], 1);
    list_tok[s2] = i;
    float wn = wa[i] / (wsum[tk] + EPS_);    // ref: w / (segsum + eps)
    float wx = wxa[i], wy = wya[i];
    wts4[i] = make_float4((1.f - wx) * (1.f - wy) * wn, wx * (1.f - wy) * wn,
                          (1.f - wx) * wy * wn,         wx * wy * wn);
}

// =========== FAT KERNEL: gather_k | conv_k' | scatter_k'' in one launch =======
// Block ranges: [0,ngath) gather, [ngath,ngath+nconv) conv, rest scatter.
// Parts are data-independent per launch; bodies are verbatim R3 semantics.
// Only valid for CC==256 (blockDim 256: conv c=tid; scatter/gather 4 slots x 64).
template<int CC>
__global__ __launch_bounds__(256)
void k_fused(const float4* __restrict__ x4,
             const int* __restrict__ off_pix, const int* __restrict__ list_pix,
             const int* __restrict__ off_tok, const int* __restrict__ list_tok,
             const int4* __restrict__ ofs4, const float4* __restrict__ wts4,
             const float* __restrict__ wT, const float* __restrict__ cb,
             const float* __restrict__ fm_r, float* __restrict__ cv_w,
             float* __restrict__ fm_w, const float* __restrict__ cv_r,
             float4* __restrict__ out4,
             int ngath, int nconv, int cbg, int cbc, int cbs) {
    constexpr int TPX = CC / 4;            // 64 threads per token/pixel slot
    int bid = blockIdx.x;
    if (bid < ngath) {
        // ---------------- gather part: 4 tokens per block (R3 body) ----------
        int lg = xcd_swz(bid, NTOK / 4);
        int slot = threadIdx.x >> 6;
        int t = threadIdx.x & 63;
        int tk = lg * 4 + slot;
        int b = tk / N_;
        int s = off_tok[tk], e = off_tok[tk + 1];
        const float4* bb = (const float4*)cv_r + (size_t)b * HW_ * TPX + t;
        float4 a = make_float4(0.f, 0.f, 0.f, 0.f);
        for (int j = s; j < e; ++j) {
            int i = list_tok[j];
            int4 o = ofs4[i];             // uniform 16B load
            float4 w = wts4[i];           // uniform 16B load (already *wn)
            float4 p0 = bb[(size_t)o.x * TPX];
            float4 p1 = bb[(size_t)o.y * TPX];
            float4 p2 = bb[(size_t)o.z * TPX];
            float4 p3 = bb[(size_t)o.w * TPX];
            a.x += w.x * p0.x + w.y * p1.x + w.z * p2.x + w.w * p3.x;
            a.y += w.x * p0.y + w.y * p1.y + w.z * p2.y + w.w * p3.y;
            a.z += w.x * p0.z + w.y * p1.z + w.z * p2.z + w.w * p3.z;
            a.w += w.x * p0.w + w.y * p1.w + w.z * p2.w + w.w * p3.w;
        }
        out4[(size_t)tk * (C_ / 4) + cbg / 4 + t] = a;
    } else if (bid < ngath + nconv) {
        // ---------------- conv part: R3 k_conv body --------------------------
        int logical = xcd_swz(bid - ngath, NBCV);
        int b = logical / NTILE;
        int tile = logical % NTILE;
        int tx0 = (tile % (W_ / TX_)) * TX_;
        int ty0 = (tile / (W_ / TX_)) * TY_;
        int c = threadIdx.x;                          // < CC == 256
        const float* base = fm_r + (size_t)b * HW_ * CC + c;
        float v[TY_ + 2][TX_ + 2];
#pragma unroll
        for (int r = 0; r < TY_ + 2; ++r) {
            int yy = ty0 + r - 1;
            bool yok = (unsigned)yy < (unsigned)H_;
#pragma unroll
            for (int j = 0; j < TX_ + 2; ++j) {
                int xx = tx0 + j - 1;
                bool ok = yok && ((unsigned)xx < (unsigned)W_);
                v[r][j] = ok ? base[(size_t)(yy * W_ + xx) * CC] : 0.f;
            }
        }
        int cg = cbc + c;
        float k0 = wT[0 * C_ + cg], k1 = wT[1 * C_ + cg], k2 = wT[2 * C_ + cg];
        float k3 = wT[3 * C_ + cg], k4 = wT[4 * C_ + cg], k5 = wT[5 * C_ + cg];
        float k6 = wT[6 * C_ + cg], k7 = wT[7 * C_ + cg], k8 = wT[8 * C_ + cg];
        float bias = cb[cg];
        float* ob = cv_w + (size_t)b * HW_ * CC + c;
#pragma unroll
        for (int r = 0; r < TY_; ++r) {
#pragma unroll
            for (int j = 0; j < TX_; ++j) {
                float acc = bias
                    + k0 * v[r][j]     + k1 * v[r][j + 1]     + k2 * v[r][j + 2]
                    + k3 * v[r + 1][j] + k4 * v[r + 1][j + 1] + k5 * v[r + 1][j + 2]
                    + k6 * v[r + 2][j] + k7 * v[r + 2][j + 1] + k8 * v[r + 2][j + 2];
                ob[(size_t)((ty0 + r) * W_ + tx0 + j) * CC] = acc;
            }
        }
    } else {
        // ---------------- scatter part: 4 pixels per block (R3 body) ---------
        int lg = xcd_swz(bid - ngath - nconv, NPIX / 4);
        int slot = threadIdx.x >> 6;
        int t = threadIdx.x & 63;
        int pk = lg * 4 + slot;
        int s = off_pix[pk], e = off_pix[pk + 1];
        float4 a = make_float4(0.f, 0.f, 0.f, 0.f);
        for (int j = s; j < e; ++j) {
            int row = list_pix[j];        // b*N + tok
            float4 v = x4[(size_t)row * (C_ / 4) + cbs / 4 + t];
            a.x += v.x; a.y += v.y; a.z += v.z; a.w += v.w;
        }
        float sc = 1.f / ((float)(e - s) + EPS_);
        a.x *= sc; a.y *= sc; a.z *= sc; a.w *= sc;
        ((float4*)fm_w)[(size_t)pk * TPX + t] = a;
    }
}

// ---------------- R3 fallback trio (used only if workspace is small) ----------
template<int CC>
__global__ __launch_bounds__(CC / 4)
void k_scat_s(const float4* __restrict__ x4, const int* __restrict__ off_pix,
              const int* __restrict__ list_pix, float4* __restrict__ fmap4,
              int cbase4) {
    int pk = xcd_swz(blockIdx.x, NPIX);
    int t = threadIdx.x;
    int s = off_pix[pk], e = off_pix[pk + 1];
    float4 a = make_float4(0.f, 0.f, 0.f, 0.f);
    for (int j = s; j < e; ++j) {
        int row = list_pix[j];
        float4 v = x4[(size_t)row * (C_ / 4) + cbase4 + t];
        a.x += v.x; a.y += v.y; a.z += v.z; a.w += v.w;
    }
    float sc = 1.f / ((float)(e - s) + EPS_);
    a.x *= sc; a.y *= sc; a.z *= sc; a.w *= sc;
    fmap4[(size_t)pk * (CC / 4) + t] = a;
}

template<int CC>
__global__ __launch_bounds__(CC)
void k_conv_s(const float* __restrict__ fmap, const float* __restrict__ wT,
              const float* __restrict__ cb, float* __restrict__ out, int cbase) {
    int logical = xcd_swz(blockIdx.x, NBCV);
    int b = logical / NTILE;
    int tile = logical % NTILE;
    int tx0 = (tile % (W_ / TX_)) * TX_;
    int ty0 = (tile / (W_ / TX_)) * TY_;
    int c = threadIdx.x;
    const float* base = fmap + (size_t)b * HW_ * CC + c;
    float v[TY_ + 2][TX_ + 2];
#pragma unroll
    for (int r = 0; r < TY_ + 2; ++r) {
        int yy = ty0 + r - 1;
        bool yok = (unsigned)yy < (unsigned)H_;
#pragma unroll
        for (int j = 0; j < TX_ + 2; ++j) {
            int xx = tx0 + j - 1;
            bool ok = yok && ((unsigned)xx < (unsigned)W_);
            v[r][j] = ok ? base[(size_t)(yy * W_ + xx) * CC] : 0.f;
        }
    }
    int cg = cbase + c;
    float k0 = wT[0 * C_ + cg], k1 = wT[1 * C_ + cg], k2 = wT[2 * C_ + cg];
    float k3 = wT[3 * C_ + cg], k4 = wT[4 * C_ + cg], k5 = wT[5 * C_ + cg];
    float k6 = wT[6 * C_ + cg], k7 = wT[7 * C_ + cg], k8 = wT[8 * C_ + cg];
    float bias = cb[cg];
    float* ob = out + (size_t)b * HW_ * CC + c;
#pragma unroll
    for (int r = 0; r < TY_; ++r) {
#pragma unroll
        for (int j = 0; j < TX_; ++j) {
            float acc = bias
                + k0 * v[r][j]     + k1 * v[r][j + 1]     + k2 * v[r][j + 2]
                + k3 * v[r + 1][j] + k4 * v[r + 1][j + 1] + k5 * v[r + 1][j + 2]
                + k6 * v[r + 2][j] + k7 * v[r + 2][j + 1] + k8 * v[r + 2][j + 2];
            ob[(size_t)((ty0 + r) * W_ + tx0 + j) * CC] = acc;
        }
    }
}

template<int CC>
__global__ __launch_bounds__(CC / 4)
void k_gath_s(const float4* __restrict__ conv4, const int* __restrict__ off_tok,
              const int* __restrict__ list_tok, const int4* __restrict__ ofs4,
              const float4* __restrict__ wts4, float4* __restrict__ out4,
              int cbase4) {
    int tk = xcd_swz(blockIdx.x, NTOK);
    int t = threadIdx.x;
    int b = tk / N_;
    int s = off_tok[tk], e = off_tok[tk + 1];
    const float4* bb = conv4 + (size_t)b * HW_ * (CC / 4) + t;
    float4 a = make_float4(0.f, 0.f, 0.f, 0.f);
    for (int j = s; j < e; ++j) {
        int i = list_tok[j];
        int4 o = ofs4[i];
        float4 w = wts4[i];
        float4 p0 = bb[(size_t)o.x * (CC / 4)];
        float4 p1 = bb[(size_t)o.y * (CC / 4)];
        float4 p2 = bb[(size_t)o.z * (CC / 4)];
        float4 p3 = bb[(size_t)o.w * (CC / 4)];
        a.x += w.x * p0.x + w.y * p1.x + w.z * p2.x + w.w * p3.x;
        a.y += w.x * p0.y + w.y * p1.y + w.z * p2.y + w.w * p3.y;
        a.z += w.x * p0.z + w.y * p1.z + w.z * p2.z + w.w * p3.z;
        a.w += w.x * p0.w + w.y * p1.w + w.z * p2.w + w.w * p3.w;
    }
    out4[(size_t)tk * (C_ / 4) + cbase4 + t] = a;
}

template<int CC>
static void run_chunks(const float4* x4, const int* off_pix, const int* list_pix,
                       const int* off_tok, const int* list_tok,
                       const int4* ofs4, const float4* wts4,
                       const float* wT, const float* cb,
                       float* fmap, float* convout, float* out,
                       hipStream_t stream) {
    constexpr int NCH = C_ / CC;
    for (int chunk = 0; chunk < NCH; ++chunk) {
        int cbase = chunk * CC;
        k_scat_s<CC><<<NPIX, CC / 4, 0, stream>>>(
            x4, off_pix, list_pix, (float4*)fmap, cbase / 4);
        k_conv_s<CC><<<NBCV, CC, 0, stream>>>(fmap, wT, cb, convout, cbase);
        k_gath_s<CC><<<NTOK, CC / 4, 0, stream>>>(
            (const float4*)convout, off_tok, list_tok, ofs4, wts4,
            (float4*)out, cbase / 4);
    }
}

extern "C" void kernel_launch(void* const* d_in, const int* in_sizes, int n_in,
                              void* d_out, int out_size, void* d_ws, size_t ws_size,
                              hipStream_t stream) {
    const float* x        = (const float*)d_in[0];
    // d_in[1] = loc (unused by reference)
    const float* loc_orig = (const float*)d_in[2];
    const int*   idx_agg  = (const int*)d_in[3];
    const float* agg_w    = (const float*)d_in[4];
    // d_in[5]=H (64), d_in[6]=W (48) fixed
    const float* conv_w   = (const float*)d_in[7];
    const float* conv_b   = (const float*)d_in[8];
    float* out = (float*)d_out;

    char* wsp = (char*)d_ws;
    size_t o = 0;
    auto alloc = [&](size_t bytes) -> void* {
        o = (o + 255) & ~(size_t)255;
        void* p = wsp + o;
        o += bytes;
        return p;
    };
    float*  wT       = (float*)alloc(C_ * 9 * sizeof(float));
    int*    pixkey   = (int*)alloc(NPTS * sizeof(int));
    int4*   ofs4     = (int4*)alloc(NPTS * sizeof(int4));
    float*  wxa      = (float*)alloc(NPTS * sizeof(float));
    float*  wya      = (float*)alloc(NPTS * sizeof(float));
    float*  wa       = (float*)alloc(NPTS * sizeof(float));
    float4* wts4     = (float4*)alloc(NPTS * sizeof(float4));
    // contiguous zero region: cnt_pix | cnt_tok | wsum
    int*    cnt_pix  = (int*)alloc((size_t)NSCAN * sizeof(int)
                                   + (size_t)NTOK * sizeof(float));
    int*    cnt_tok  = cnt_pix + NPIX;
    float*  wsum     = (float*)(cnt_tok + NTOK);
    int*    pre      = (int*)alloc((size_t)NSCAN * sizeof(int));
    int*    bsum     = (int*)alloc(NBALL * sizeof(int));
    int*    bbase    = (int*)alloc(NBALL * sizeof(int));
    int*    off_pix  = (int*)alloc((size_t)(NPIX + 1) * sizeof(int));
    int*    off_tok  = (int*)alloc((size_t)(NTOK + 1) * sizeof(int));
    int*    cur_pix  = (int*)alloc((size_t)NPIX * sizeof(int));
    int*    cur_tok  = (int*)alloc((size_t)NTOK * sizeof(int));
    int*    list_pix = (int*)alloc(NPTS * sizeof(int));
    int*    list_tok = (int*)alloc(NPTS * sizeof(int));

    size_t small_end = (o + 255) & ~(size_t)255;
    size_t slab = (size_t)B_ * HW_ * 256 * sizeof(float);   // 50.3 MB @ CC=256
    size_t avail = (ws_size > small_end + 1024) ? ws_size - small_end - 1024 : 0;

    hipMemsetAsync(cnt_pix, 0,
                   (size_t)NSCAN * sizeof(int) + (size_t)NTOK * sizeof(float),
                   stream);
    k_pre<<<NBPT + (C_ * 9 + 255) / 256, 256, 0, stream>>>(
        loc_orig, idx_agg, agg_w, conv_w, wT,
        pixkey, ofs4, wxa, wya, wa, cnt_pix, cnt_tok, wsum);
    k_scanA<<<NBALL, 256, 0, stream>>>(cnt_pix, pre, bsum);
    k_scanB<<<1, 256, 0, stream>>>(bsum, bbase, off_pix, off_tok);
    k_scanC<<<NBALL, 256, 0, stream>>>(pre, bbase, off_pix, cur_pix, off_tok, cur_tok);
    k_fill<<<NPTS / 256, 256, 0, stream>>>(pixkey, idx_agg, wxa, wya, wa, wsum,
                                           cur_pix, cur_tok, list_pix, list_tok, wts4);

    const float4* x4 = (const float4*)x;

    if (avail >= 4 * slab) {
        // ---- pipelined fat-launch path: 5 launches, 4 ping-pong slabs -------
        float* s0 = (float*)alloc(slab);   // fmap  chunk even
        float* s1 = (float*)alloc(slab);   // fmap  chunk odd
        float* s2 = (float*)alloc(slab);   // conv  chunk even
        float* s3 = (float*)alloc(slab);   // conv  chunk odd
        const int NG = NTOK / 4, NC = NBCV, NS = NPIX / 4;
        auto L = [&](int ng, int nc, int ns,
                     const float* fmr, float* cvw, float* fmw, const float* cvr,
                     int cbg, int cbc, int cbs) {
            k_fused<256><<<ng + nc + ns, 256, 0, stream>>>(
                x4, off_pix, list_pix, off_tok, list_tok, ofs4, wts4,
                wT, conv_b, fmr, cvw, fmw, cvr, (float4*)out,
                ng, nc, cbg, cbc, cbs);
        };
        // L0: scatter c0 -> s0
        L(0,  0,  NS, nullptr, nullptr, s0, nullptr,   0,   0,   0);
        // L1: conv c0 (s0->s2)  ||  scatter c1 -> s1
        L(0,  NC, NS, s0, s2, s1, nullptr,             0,   0, 256);
        // L2: gather c0 (s2)  ||  conv c1 (s1->s3)  ||  scatter c2 -> s0
        L(NG, NC, NS, s1, s3, s0, s2,                  0, 256, 512);
        // L3: gather c1 (s3)  ||  conv c2 (s0->s2)
        L(NG, NC, 0,  s0, s2, nullptr, s3,           256, 512,   0);
        // L4: gather c2 (s2)
        L(NG, 0,  0,  nullptr, nullptr, nullptr, s2, 512,   0,   0);
    } else {
        // ---- R3 serial fallback ---------------------------------------------
        size_t perchan = (size_t)B_ * HW_ * 2 * sizeof(float);
        int cc = 8;
        const int ladder[5] = {256, 128, 64, 32, 16};
        for (int k = 0; k < 5; ++k)
            if (avail >= (size_t)ladder[k] * perchan) { cc = ladder[k]; break; }
        float* fmap    = (float*)alloc((size_t)B_ * HW_ * cc * sizeof(float));
        float* convout = (float*)alloc((size_t)B_ * HW_ * cc * sizeof(float));
        switch (cc) {
            case 256: run_chunks<256>(x4, off_pix, list_pix, off_tok, list_tok,
                                      ofs4, wts4, wT, conv_b, fmap, convout, out,
                                      stream); break;
            case 128: run_chunks<128>(x4, off_pix, list_pix, off_tok, list_tok,
                                      ofs4, wts4, wT, conv_b, fmap, convout, out,
                                      stream); break;
            case  64: run_chunks< 64>(x4, off_pix, list_pix, off_tok, list_tok,
                                      ofs4, wts4, wT, conv_b, fmap, convout, out,
                                      stream); break;
            case  32: run_chunks< 32>(x4, off_pix, list_pix, off_tok, list_tok,
                                      ofs4, wts4, wT, conv_b, fmap, convout, out,
                                      stream); break;
            case  16: run_chunks< 16>(x4, off_pix, list_pix, off_tok, list_tok,
                                      ofs4, wts4, wT, conv_b, fmap, convout, out,
                                      stream); break;
            default:  run_chunks<  8>(x4, off_pix, list_pix, off_tok, list_tok,
                                      ofs4, wts4, wT, conv_b, fmap, convout, out,
                                      stream); break;
        }
    }
}

// Round 7
// 316.407 us; speedup vs baseline: 1.0881x; 1.0881x over previous
//
#include <hip/hip_runtime.h>

// Problem constants (fixed by setup_inputs in the reference; fp32 world)
#define B_    16
#define N_    1536
#define C_    768
#define N0_   3072
#define H_    64
#define W_    48
#define HW_   (H_ * W_)        // 3072
#define NPTS  (B_ * N0_)       // 49152
#define NTOK  (B_ * N_)        // 24576
#define NPIX  (B_ * HW_)       // 49152
#define NSCAN (NPIX + NTOK)    // 73728 = 288 * 256
#define NBP   (NPIX / 256)     // 192
#define NBALL (NSCAN / 256)    // 288
#define EPS_  1e-6f
#define TY_   4                // conv tile rows per block
#define TX_   8                // conv tile cols per block
#define HTY_  (TY_ + 2)        // 6 halo rows
#define HTX_  (TX_ + 2)        // 10 halo cols
#define NHALO (HTY_ * HTX_)    // 60 halo pixels
#define NTILE ((W_ / TX_) * (H_ / TY_))   // 96 tiles per batch
#define NBCV  (B_ * NTILE)                // 1536 conv blocks (divisible by 8)

// Bijective XCD swizzle (grid % 8 == 0): XCD g gets the contiguous logical
// range [g*(n/8), (g+1)*(n/8)) -> batch b lands on XCD b/2 in ALL kernels,
// so producer writes and consumer reads of a batch share the same L2.
__device__ __forceinline__ int xcd_swz(int bid, int n) {
    return (bid & 7) * (n >> 3) + (bid >> 3);
}

// ---------------- transpose conv weights to [9][C] for coalesced reads --------
__global__ void k_wT(const float* __restrict__ w, float* __restrict__ wT) {
    int i = blockIdx.x * blockDim.x + threadIdx.x;   // over C_*9
    if (i < C_ * 9) { int c = i / 9, k = i - c * 9; wT[k * C_ + c] = w[i]; }
}

// ---------------- per-point precompute + histograms + wsum ----------------
__global__ void k_points(const float* __restrict__ loc_orig,
                         const int* __restrict__ idx_agg,
                         const float* __restrict__ agg_w,
                         int* __restrict__ pixkey, int4* __restrict__ ofs4,
                         float* __restrict__ wxa, float* __restrict__ wya,
                         float* __restrict__ wa,
                         int* __restrict__ cnt_pix, int* __restrict__ cnt_tok,
                         float* __restrict__ wsum) {
    int i = blockIdx.x * blockDim.x + threadIdx.x;
    if (i >= NPTS) return;
    int b = i / N0_;
    float lx = loc_orig[2 * (size_t)i];
    float ly = loc_orig[2 * (size_t)i + 1];
    lx = fminf(fmaxf(lx, -1.f), 1.f);
    ly = fminf(fmaxf(ly, -1.f), 1.f);
    float px = 0.5f * (lx + 1.f) * (float)W_ - 0.5f;   // matches np ref exactly
    float py = 0.5f * (ly + 1.f) * (float)H_ - 0.5f;
    // nearest pixel (round-half-even == np.round)
    int ixn = min(max((int)rintf(px), 0), W_ - 1);
    int iyn = min(max((int)rintf(py), 0), H_ - 1);
    int pk = b * HW_ + iyn * W_ + ixn;
    pixkey[i] = pk;
    // bilinear corners (clipped), weights per reference (may be negative at edges)
    int x0 = min(max((int)floorf(px), 0), W_ - 1);
    int x1 = min(x0 + 1, W_ - 1);
    int y0 = min(max((int)floorf(py), 0), H_ - 1);
    int y1 = min(y0 + 1, H_ - 1);
    wxa[i] = fminf((float)x1, px) - (float)x0;
    wya[i] = fminf((float)y1, py) - (float)y0;
    ofs4[i] = make_int4(y0 * W_ + x0, y0 * W_ + x1, y1 * W_ + x0, y1 * W_ + x1);
    float w = agg_w[i];
    wa[i] = w;
    atomicAdd(&cnt_pix[pk], 1);
    int tk = b * N_ + idx_agg[i];
    atomicAdd(&cnt_tok[tk], 1);
    atomicAdd(&wsum[tk], w);
}

// ---------------- hierarchical scan over contiguous cnt_pix|cnt_tok -----------
__global__ __launch_bounds__(256)
void k_scanA(const int* __restrict__ cnt, int* __restrict__ pre, int* __restrict__ bsum) {
    __shared__ int sh[256];
    int b = blockIdx.x, t = threadIdx.x;
    int i = b * 256 + t;
    int v = cnt[i];
    sh[t] = v;
    __syncthreads();
    for (int d = 1; d < 256; d <<= 1) {
        int x = sh[t];
        int y = (t >= d) ? sh[t - d] : 0;
        __syncthreads();
        sh[t] = x + y;
        __syncthreads();
    }
    pre[i] = sh[t] - v;            // exclusive within block
    if (t == 255) bsum[b] = sh[255];
}

__global__ __launch_bounds__(256)
void k_scanB(const int* __restrict__ bsum, int* __restrict__ bbase,
             int* __restrict__ off_pix, int* __restrict__ off_tok) {
    __shared__ int sh[256];
    int t = threadIdx.x;
    int v = (t < NBP) ? bsum[t] : 0;
    sh[t] = v;
    __syncthreads();
    for (int d = 1; d < 256; d <<= 1) {
        int x = sh[t];
        int y = (t >= d) ? sh[t - d] : 0;
        __syncthreads();
        sh[t] = x + y;
        __syncthreads();
    }
    if (t < NBP) bbase[t] = sh[t] - v;
    __syncthreads();
    int nbt = NBALL - NBP;
    v = (t < nbt) ? bsum[NBP + t] : 0;
    sh[t] = v;
    __syncthreads();
    for (int d = 1; d < 256; d <<= 1) {
        int x = sh[t];
        int y = (t >= d) ? sh[t - d] : 0;
        __syncthreads();
        sh[t] = x + y;
        __syncthreads();
    }
    if (t < nbt) bbase[NBP + t] = sh[t] - v;
    if (t == 0) { off_pix[NPIX] = NPTS; off_tok[NTOK] = NPTS; }
}

__global__ __launch_bounds__(256)
void k_scanC(const int* __restrict__ pre, const int* __restrict__ bbase,
             int* __restrict__ off_pix, int* __restrict__ cur_pix,
             int* __restrict__ off_tok, int* __restrict__ cur_tok) {
    int b = blockIdx.x, t = threadIdx.x;
    int i = b * 256 + t;
    int val = pre[i] + bbase[b];
    if (b < NBP) { off_pix[i] = val; cur_pix[i] = val; }
    else { int j = i - NPIX; off_tok[j] = val; cur_tok[j] = val; }
}

// ---------------- CSR fill + premultiplied bilinear weights -------------------
__global__ void k_fill(const int* __restrict__ pixkey, const int* __restrict__ idx_agg,
                       const float* __restrict__ wxa, const float* __restrict__ wya,
                       const float* __restrict__ wa, const float* __restrict__ wsum,
                       int* __restrict__ cur_pix, int* __restrict__ cur_tok,
                       int* __restrict__ list_pix, int* __restrict__ list_tok,
                       float4* __restrict__ wts4) {
    int i = blockIdx.x * blockDim.x + threadIdx.x;
    if (i >= NPTS) return;
    int b = i / N0_;
    int tok = idx_agg[i];
    int tk = b * N_ + tok;
    int s1 = atomicAdd(&cur_pix[pixkey[i]], 1);
    list_pix[s1] = tk;                 // direct x-row index for scatter
    int s2 = atomicAdd(&cur_tok[tk], 1);
    list_tok[s2] = i;
    float wn = wa[i] / (wsum[tk] + EPS_);    // ref: w / (segsum + eps)
    float wx = wxa[i], wy = wya[i];
    wts4[i] = make_float4((1.f - wx) * (1.f - wy) * wn, wx * (1.f - wy) * wn,
                          (1.f - wx) * wy * wn,         wx * wy * wn);
}

// ======== FUSED token2map + depthwise 3x3 via LDS halo (parallel build) =======
// 512 threads. Phase 1: 8 waves build the 60-pixel halo in LDS, 8 pixels at a
// time (<=8 serial CSR walks per wave, vs R2's 60 -> chain 7.5x shorter).
// Phase 2: 2 row-halves x 256 channels run the register-tiled conv from LDS.
// Eliminates the fmap HBM round-trip (~100 MB/chunk) and one launch per chunk.
template<int CC>   // CC == 256 only
__global__ __launch_bounds__(512, 4)
void k_sconv(const float4* __restrict__ x4, const int* __restrict__ off_pix,
             const int* __restrict__ list_pix, const float* __restrict__ wT,
             const float* __restrict__ cb, float* __restrict__ out, int cbase) {
    __shared__ float4 sh4[NHALO * (CC / 4)];     // 60*64*16B = 60 KB
    int logical = xcd_swz(blockIdx.x, NBCV);     // batch b -> XCD b/2
    int b = logical / NTILE;
    int tile = logical % NTILE;
    int tx0 = (tile % (W_ / TX_)) * TX_;
    int ty0 = (tile / (W_ / TX_)) * TY_;
    {
        int slot = threadIdx.x >> 6;             // wave id, 0..7
        int t = threadIdx.x & 63;                // float4 lane over CC
#pragma unroll
        for (int it = 0; it < (NHALO + 7) / 8; ++it) {
            int hp = it * 8 + slot;              // halo pixel [0, 60)
            if (hp < NHALO) {
                int hy = hp / HTX_, hx = hp - hy * HTX_;
                int yy = ty0 + hy - 1, xx = tx0 + hx - 1;
                float4 a = make_float4(0.f, 0.f, 0.f, 0.f);
                if ((unsigned)yy < (unsigned)H_ && (unsigned)xx < (unsigned)W_) {
                    int pk = b * HW_ + yy * W_ + xx;
                    int s = off_pix[pk], e = off_pix[pk + 1];
                    for (int j = s; j < e; ++j) {
                        int row = list_pix[j];               // wave-uniform
                        float4 v = x4[(size_t)row * (C_ / 4) + (cbase >> 2) + t];
                        a.x += v.x; a.y += v.y; a.z += v.z; a.w += v.w;
                    }
                    float sc = 1.f / ((float)(e - s) + EPS_);
                    a.x *= sc; a.y *= sc; a.z *= sc; a.w *= sc;
                }
                sh4[hp * (CC / 4) + t] = a;
            }
        }
    }
    __syncthreads();
    // ---- conv phase: thread = (row-half, channel) ----------------------------
    int c = threadIdx.x & (CC - 1);
    int half = threadIdx.x >> 8;                 // 0: rows 0-1, 1: rows 2-3
    const float* sh = (const float*)sh4;
    float v[TY_ / 2 + 2][HTX_];                  // 4 x 10 halo rows for my half
#pragma unroll
    for (int r = 0; r < TY_ / 2 + 2; ++r)
#pragma unroll
        for (int j = 0; j < HTX_; ++j)
            v[r][j] = sh[((half * 2 + r) * HTX_ + j) * CC + c];
    int cg = cbase + c;
    float k0 = wT[0 * C_ + cg], k1 = wT[1 * C_ + cg], k2 = wT[2 * C_ + cg];
    float k3 = wT[3 * C_ + cg], k4 = wT[4 * C_ + cg], k5 = wT[5 * C_ + cg];
    float k6 = wT[6 * C_ + cg], k7 = wT[7 * C_ + cg], k8 = wT[8 * C_ + cg];
    float bias = cb[cg];
    float* ob = out + (size_t)b * HW_ * CC + c;
#pragma unroll
    for (int r = 0; r < TY_ / 2; ++r) {
#pragma unroll
        for (int j = 0; j < TX_; ++j) {
            float acc = bias
                + k0 * v[r][j]     + k1 * v[r][j + 1]     + k2 * v[r][j + 2]
                + k3 * v[r + 1][j] + k4 * v[r + 1][j + 1] + k5 * v[r + 1][j + 2]
                + k6 * v[r + 2][j] + k7 * v[r + 2][j + 1] + k8 * v[r + 2][j + 2];
            ob[(size_t)((ty0 + half * 2 + r) * W_ + tx0 + j) * CC] = acc;
        }
    }
}

// ---------------- map2token: per-token float4 gather (R3 verbatim) ------------
template<int CC>
__global__ __launch_bounds__(CC / 4)
void k_gather(const float4* __restrict__ conv4, const int* __restrict__ off_tok,
              const int* __restrict__ list_tok, const int4* __restrict__ ofs4,
              const float4* __restrict__ wts4, float4* __restrict__ out4,
              int cbase4) {
    int tk = xcd_swz(blockIdx.x, NTOK);   // batch b -> XCD b/2
    int t = threadIdx.x;                  // [0, CC/4)
    int b = tk / N_;
    int s = off_tok[tk], e = off_tok[tk + 1];
    const float4* bb = conv4 + (size_t)b * HW_ * (CC / 4) + t;
    float4 a = make_float4(0.f, 0.f, 0.f, 0.f);
    for (int j = s; j < e; ++j) {
        int i = list_tok[j];
        int4 o = ofs4[i];             // uniform 16B load
        float4 w = wts4[i];           // uniform 16B load (already *wn)
        float4 p0 = bb[(size_t)o.x * (CC / 4)];
        float4 p1 = bb[(size_t)o.y * (CC / 4)];
        float4 p2 = bb[(size_t)o.z * (CC / 4)];
        float4 p3 = bb[(size_t)o.w * (CC / 4)];
        a.x += w.x * p0.x + w.y * p1.x + w.z * p2.x + w.w * p3.x;
        a.y += w.x * p0.y + w.y * p1.y + w.z * p2.y + w.w * p3.y;
        a.z += w.x * p0.z + w.y * p1.z + w.z * p2.z + w.w * p3.z;
        a.w += w.x * p0.w + w.y * p1.w + w.z * p2.w + w.w * p3.w;
    }
    out4[(size_t)tk * (C_ / 4) + cbase4 + t] = a;
}

// ---------------- R3 fallback trio (only if workspace is small) ---------------
template<int CC>
__global__ __launch_bounds__(CC / 4)
void k_scat_s(const float4* __restrict__ x4, const int* __restrict__ off_pix,
              const int* __restrict__ list_pix, float4* __restrict__ fmap4,
              int cbase4) {
    int pk = xcd_swz(blockIdx.x, NPIX);
    int t = threadIdx.x;
    int s = off_pix[pk], e = off_pix[pk + 1];
    float4 a = make_float4(0.f, 0.f, 0.f, 0.f);
    for (int j = s; j < e; ++j) {
        int row = list_pix[j];
        float4 v = x4[(size_t)row * (C_ / 4) + cbase4 + t];
        a.x += v.x; a.y += v.y; a.z += v.z; a.w += v.w;
    }
    float sc = 1.f / ((float)(e - s) + EPS_);
    a.x *= sc; a.y *= sc; a.z *= sc; a.w *= sc;
    fmap4[(size_t)pk * (CC / 4) + t] = a;
}

template<int CC>
__global__ __launch_bounds__(CC)
void k_conv_s(const float* __restrict__ fmap, const float* __restrict__ wT,
              const float* __restrict__ cb, float* __restrict__ out, int cbase) {
    int logical = xcd_swz(blockIdx.x, NBCV);
    int b = logical / NTILE;
    int tile = logical % NTILE;
    int tx0 = (tile % (W_ / TX_)) * TX_;
    int ty0 = (tile / (W_ / TX_)) * TY_;
    int c = threadIdx.x;
    const float* base = fmap + (size_t)b * HW_ * CC + c;
    float v[TY_ + 2][TX_ + 2];
#pragma unroll
    for (int r = 0; r < TY_ + 2; ++r) {
        int yy = ty0 + r - 1;
        bool yok = (unsigned)yy < (unsigned)H_;
#pragma unroll
        for (int j = 0; j < TX_ + 2; ++j) {
            int xx = tx0 + j - 1;
            bool ok = yok && ((unsigned)xx < (unsigned)W_);
            v[r][j] = ok ? base[(size_t)(yy * W_ + xx) * CC] : 0.f;
        }
    }
    int cg = cbase + c;
    float k0 = wT[0 * C_ + cg], k1 = wT[1 * C_ + cg], k2 = wT[2 * C_ + cg];
    float k3 = wT[3 * C_ + cg], k4 = wT[4 * C_ + cg], k5 = wT[5 * C_ + cg];
    float k6 = wT[6 * C_ + cg], k7 = wT[7 * C_ + cg], k8 = wT[8 * C_ + cg];
    float bias = cb[cg];
    float* ob = out + (size_t)b * HW_ * CC + c;
#pragma unroll
    for (int r = 0; r < TY_; ++r) {
#pragma unroll
        for (int j = 0; j < TX_; ++j) {
            float acc = bias
                + k0 * v[r][j]     + k1 * v[r][j + 1]     + k2 * v[r][j + 2]
                + k3 * v[r + 1][j] + k4 * v[r + 1][j + 1] + k5 * v[r + 1][j + 2]
                + k6 * v[r + 2][j] + k7 * v[r + 2][j + 1] + k8 * v[r + 2][j + 2];
            ob[(size_t)((ty0 + r) * W_ + tx0 + j) * CC] = acc;
        }
    }
}

template<int CC>
static void run_chunks(const float4* x4, const int* off_pix, const int* list_pix,
                       const int* off_tok, const int* list_tok,
                       const int4* ofs4, const float4* wts4,
                       const float* wT, const float* cb,
                       float* fmap, float* convout, float* out,
                       hipStream_t stream) {
    constexpr int NCH = C_ / CC;
    for (int chunk = 0; chunk < NCH; ++chunk) {
        int cbase = chunk * CC;
        k_scat_s<CC><<<NPIX, CC / 4, 0, stream>>>(
            x4, off_pix, list_pix, (float4*)fmap, cbase / 4);
        k_conv_s<CC><<<NBCV, CC, 0, stream>>>(fmap, wT, cb, convout, cbase);
        k_gather<CC><<<NTOK, CC / 4, 0, stream>>>(
            (const float4*)convout, off_tok, list_tok, ofs4, wts4,
            (float4*)out, cbase / 4);
    }
}

extern "C" void kernel_launch(void* const* d_in, const int* in_sizes, int n_in,
                              void* d_out, int out_size, void* d_ws, size_t ws_size,
                              hipStream_t stream) {
    const float* x        = (const float*)d_in[0];
    // d_in[1] = loc (unused by reference)
    const float* loc_orig = (const float*)d_in[2];
    const int*   idx_agg  = (const int*)d_in[3];
    const float* agg_w    = (const float*)d_in[4];
    // d_in[5]=H (64), d_in[6]=W (48) fixed
    const float* conv_w   = (const float*)d_in[7];
    const float* conv_b   = (const float*)d_in[8];
    float* out = (float*)d_out;

    char* wsp = (char*)d_ws;
    size_t o = 0;
    auto alloc = [&](size_t bytes) -> void* {
        o = (o + 255) & ~(size_t)255;
        void* p = wsp + o;
        o += bytes;
        return p;
    };
    float*  wT       = (float*)alloc(C_ * 9 * sizeof(float));
    int*    pixkey   = (int*)alloc(NPTS * sizeof(int));
    int4*   ofs4     = (int4*)alloc(NPTS * sizeof(int4));
    float*  wxa      = (float*)alloc(NPTS * sizeof(float));
    float*  wya      = (float*)alloc(NPTS * sizeof(float));
    float*  wa       = (float*)alloc(NPTS * sizeof(float));
    float4* wts4     = (float4*)alloc(NPTS * sizeof(float4));
    // contiguous zero region: cnt_pix | cnt_tok | wsum
    int*    cnt_pix  = (int*)alloc((size_t)NSCAN * sizeof(int)
                                   + (size_t)NTOK * sizeof(float));
    int*    cnt_tok  = cnt_pix + NPIX;
    float*  wsum     = (float*)(cnt_tok + NTOK);
    int*    pre      = (int*)alloc((size_t)NSCAN * sizeof(int));
    int*    bsum     = (int*)alloc(NBALL * sizeof(int));
    int*    bbase    = (int*)alloc(NBALL * sizeof(int));
    int*    off_pix  = (int*)alloc((size_t)(NPIX + 1) * sizeof(int));
    int*    off_tok  = (int*)alloc((size_t)(NTOK + 1) * sizeof(int));
    int*    cur_pix  = (int*)alloc((size_t)NPIX * sizeof(int));
    int*    cur_tok  = (int*)alloc((size_t)NTOK * sizeof(int));
    int*    list_pix = (int*)alloc(NPTS * sizeof(int));
    int*    list_tok = (int*)alloc(NPTS * sizeof(int));

    size_t small_end = (o + 255) & ~(size_t)255;
    size_t slab = (size_t)B_ * HW_ * 256 * sizeof(float);   // 50.3 MB @ CC=256
    size_t avail = (ws_size > small_end + 1024) ? ws_size - small_end - 1024 : 0;

    hipMemsetAsync(cnt_pix, 0,
                   (size_t)NSCAN * sizeof(int) + (size_t)NTOK * sizeof(float),
                   stream);
    k_wT<<<(C_ * 9 + 255) / 256, 256, 0, stream>>>(conv_w, wT);
    k_points<<<NPTS / 256, 256, 0, stream>>>(loc_orig, idx_agg, agg_w,
                                             pixkey, ofs4, wxa, wya, wa,
                                             cnt_pix, cnt_tok, wsum);
    k_scanA<<<NBALL, 256, 0, stream>>>(cnt_pix, pre, bsum);
    k_scanB<<<1, 256, 0, stream>>>(bsum, bbase, off_pix, off_tok);
    k_scanC<<<NBALL, 256, 0, stream>>>(pre, bbase, off_pix, cur_pix, off_tok, cur_tok);
    k_fill<<<NPTS / 256, 256, 0, stream>>>(pixkey, idx_agg, wxa, wya, wa, wsum,
                                           cur_pix, cur_tok, list_pix, list_tok, wts4);

    const float4* x4 = (const float4*)x;

    if (avail >= slab) {
        // ---- main path: fused scatter+conv (no fmap round-trip), then gather
        float* convout = (float*)alloc(slab);
        for (int chunk = 0; chunk < 3; ++chunk) {
            int cbase = chunk * 256;
            k_sconv<256><<<NBCV, 512, 0, stream>>>(
                x4, off_pix, list_pix, wT, conv_b, convout, cbase);
            k_gather<256><<<NTOK, 64, 0, stream>>>(
                (const float4*)convout, off_tok, list_tok, ofs4, wts4,
                (float4*)out, cbase / 4);
        }
    } else {
        // ---- R3 serial fallback ---------------------------------------------
        size_t perchan = (size_t)B_ * HW_ * 2 * sizeof(float);
        int cc = 8;
        const int ladder[5] = {256, 128, 64, 32, 16};
        for (int k = 0; k < 5; ++k)
            if (avail >= (size_t)ladder[k] * perchan) { cc = ladder[k]; break; }
        float* fmap    = (float*)alloc((size_t)B_ * HW_ * cc * sizeof(float));
        float* convout = (float*)alloc((size_t)B_ * HW_ * cc * sizeof(float));
        switch (cc) {
            case 256: run_chunks<256>(x4, off_pix, list_pix, off_tok, list_tok,
                                      ofs4, wts4, wT, conv_b, fmap, convout, out,
                                      stream); break;
            case 128: run_chunks<128>(x4, off_pix, list_pix, off_tok, list_tok,
                                      ofs4, wts4, wT, conv_b, fmap, convout, out,
                                      stream); break;
            case  64: run_chunks< 64>(x4, off_pix, list_pix, off_tok, list_tok,
                                      ofs4, wts4, wT, conv_b, fmap, convout, out,
                                      stream); break;
            case  32: run_chunks< 32>(x4, off_pix, list_pix, off_tok, list_tok,
                                      ofs4, wts4, wT, conv_b, fmap, convout, out,
                                      stream); break;
            case  16: run_chunks< 16>(x4, off_pix, list_pix, off_tok, list_tok,
                                      ofs4, wts4, wT, conv_b, fmap, convout, out,
                                      stream); break;
            default:  run_chunks<  8>(x4, off_pix, list_pix, off_tok, list_tok,
                                      ofs4, wts4, wT, conv_b, fmap, convout, out,
                                      stream); break;
        }
    }
}